// Round 3
// baseline (1435.577 us; speedup 1.0000x reference)
//
#include <hip/hip_runtime.h>
#include <stdint.h>

// GCN layer: out = prelu(W @ segsum(A_val * h[A_col] -> A_row) + b, act_a)
//            h   = prelu(Wr @ AX + br, g_a)
// R3 structure: f16 MFMA GEMMs; SpMM via single radix pass into 1563 buckets
// of 64 rows (dense block-contiguous writes -> write-combining works, unlike
// R1/R2's random 8B scatter that drained a full 64B line per edge), then
// per-bucket LDS fp32 accumulation with ds_add_f32 (conflict-free via
// permuted h layout: lane's half2 = cols {l, l+64}).

typedef _Float16 half8 __attribute__((ext_vector_type(8)));
typedef _Float16 half4 __attribute__((ext_vector_type(4)));
typedef _Float16 half2v __attribute__((ext_vector_type(2)));
typedef float floatx4 __attribute__((ext_vector_type(4)));

#define LDK 136        // GEMM LDS row stride in halfs: 128 + 8
#define SHIFT 6        // 64 rows per bucket
#define NBMAX 1600     // >= ceil(100000/64) = 1563
#define NBLK 128       // hist/scatter chunks

// ---------------- GEMM: out = prelu(X @ W^T + b) ----------------
template<bool IN_F32, bool OUT_F16, bool PERM_OUT>
__global__ __launch_bounds__(256, 2)
void gemm128_prelu(const void* __restrict__ Xv, const float* __restrict__ W,
                   const float* __restrict__ bias, const float* __restrict__ alpha_p,
                   void* __restrict__ outv, int N)
{
    __shared__ _Float16 Xs[128 * LDK];
    __shared__ _Float16 Ws[128 * LDK];
    const int tid = threadIdx.x;
    const int bm  = blockIdx.x * 128;
    const float alpha = *alpha_p;

#pragma unroll
    for (int i = 0; i < 16; ++i) {
        int c   = tid + i * 256;
        int row = c >> 5;
        int coff = (c & 31) * 4;
        float4 f = *(const float4*)(W + row * 128 + coff);
        half4 hv = { (_Float16)f.x, (_Float16)f.y, (_Float16)f.z, (_Float16)f.w };
        *(half4*)(&Ws[row * LDK + coff]) = hv;
    }
    if (IN_F32) {
        const float* X = (const float*)Xv;
#pragma unroll
        for (int i = 0; i < 16; ++i) {
            int c   = tid + i * 256;
            int row = c >> 5;
            int coff = (c & 31) * 4;
            int grow = bm + row;
            half4 hv = {};
            if (grow < N) {
                float4 f = *(const float4*)(X + (size_t)grow * 128 + coff);
                hv[0] = (_Float16)f.x; hv[1] = (_Float16)f.y;
                hv[2] = (_Float16)f.z; hv[3] = (_Float16)f.w;
            }
            *(half4*)(&Xs[row * LDK + coff]) = hv;
        }
    } else {
        const _Float16* X = (const _Float16*)Xv;
#pragma unroll
        for (int i = 0; i < 8; ++i) {
            int c   = tid + i * 256;
            int row = c >> 4;
            int coff = (c & 15) * 8;
            int grow = bm + row;
            half8 hv = {};
            if (grow < N) hv = *(const half8*)(X + (size_t)grow * 128 + coff);
            *(half8*)(&Xs[row * LDK + coff]) = hv;
        }
    }
    __syncthreads();

    const int wave = tid >> 6;
    const int lane = tid & 63;
    const int l15  = lane & 15;
    const int quad = lane >> 4;

    floatx4 acc[2][8] = {};
#pragma unroll
    for (int k0 = 0; k0 < 128; k0 += 32) {
        half8 a0 = *(const half8*)(&Xs[(wave * 32 +      l15) * LDK + k0 + quad * 8]);
        half8 a1 = *(const half8*)(&Xs[(wave * 32 + 16 + l15) * LDK + k0 + quad * 8]);
        half8 b[8];
#pragma unroll
        for (int n = 0; n < 8; ++n)
            b[n] = *(const half8*)(&Ws[(n * 16 + l15) * LDK + k0 + quad * 8]);
#pragma unroll
        for (int n = 0; n < 8; ++n) {
            acc[0][n] = __builtin_amdgcn_mfma_f32_16x16x32_f16(a0, b[n], acc[0][n], 0, 0, 0);
            acc[1][n] = __builtin_amdgcn_mfma_f32_16x16x32_f16(a1, b[n], acc[1][n], 0, 0, 0);
        }
    }

#pragma unroll
    for (int mt = 0; mt < 2; ++mt) {
#pragma unroll
        for (int n = 0; n < 8; ++n) {
#pragma unroll
            for (int r = 0; r < 4; ++r) {
                int row = bm + wave * 32 + mt * 16 + quad * 4 + r;
                int col = n * 16 + l15;
                if (row < N) {
                    float v = acc[mt][n][r] + bias[col];
                    v = (v >= 0.f) ? v : alpha * v;
                    int p = PERM_OUT ? ((col < 64) ? (2 * col) : (2 * (col - 64) + 1)) : col;
                    if (OUT_F16) ((_Float16*)outv)[(size_t)row * 128 + p] = (_Float16)v;
                    else         ((float*)outv)[(size_t)row * 128 + p]    = v;
                }
            }
        }
    }
}

// ---------------- bucket radix pass ----------------
// hist: per-(bucket, chunk-block) counts, layout hist_g[bucket*NBLK + blk]
__global__ __launch_bounds__(256)
void bucket_hist(const int* __restrict__ rows, int* __restrict__ hist_g,
                 int E, int chunk, int NB)
{
    __shared__ int lh[NBMAX];
    int tid = threadIdx.x, blk = blockIdx.x;
    for (int i = tid; i < NB; i += 256) lh[i] = 0;
    __syncthreads();
    int s = blk * chunk, e = min(E, s + chunk);
    for (int i = s + tid; i < e; i += 256)
        atomicAdd(&lh[rows[i] >> SHIFT], 1);
    __syncthreads();
    for (int b = tid; b < NB; b += 256)
        hist_g[b * NBLK + blk] = lh[b];
}

// per-bucket exclusive scan over NBLK block-counts (in place) + bucket total
__global__ __launch_bounds__(NBLK)
void bucket_scan1(int* __restrict__ hist_g, int* __restrict__ tot)
{
    __shared__ int sd[NBLK];
    int b = blockIdx.x, t = threadIdx.x;
    int v = hist_g[b * NBLK + t];
    sd[t] = v;
    __syncthreads();
    for (int off = 1; off < NBLK; off <<= 1) {
        int x = (t >= off) ? sd[t - off] : 0;
        __syncthreads();
        sd[t] += x;
        __syncthreads();
    }
    hist_g[b * NBLK + t] = sd[t] - v;   // exclusive
    if (t == NBLK - 1) tot[b] = sd[t];
}

// exclusive scan of bucket totals -> bkt_ptr[0..NB], bkt_ptr[NB]=E. 1 block x 1024.
__global__ __launch_bounds__(1024)
void bucket_scan2(const int* __restrict__ tot, int* __restrict__ bkt_ptr, int NB, int E)
{
    __shared__ int sd[1024];
    int t = threadIdx.x;
    int a  = (2 * t     < NB) ? tot[2 * t]     : 0;
    int b2 = (2 * t + 1 < NB) ? tot[2 * t + 1] : 0;
    sd[t] = a + b2;
    __syncthreads();
    for (int off = 1; off < 1024; off <<= 1) {
        int x = (t >= off) ? sd[t - off] : 0;
        __syncthreads();
        sd[t] += x;
        __syncthreads();
    }
    int base = (t == 0) ? 0 : sd[t - 1];
    if (2 * t     < NB) bkt_ptr[2 * t]     = base;
    if (2 * t + 1 < NB) bkt_ptr[2 * t + 1] = base + a;
    if (t == 0) bkt_ptr[NB] = E;
}

// scatter edges into bucket-contiguous storage; packed (col | rloc<<20, valbits)
__global__ __launch_bounds__(256)
void bucket_scatter(const int* __restrict__ rows, const int* __restrict__ cols,
                    const float* __restrict__ vals, const int* __restrict__ bkt_ptr,
                    const int* __restrict__ hist_g, uint2* __restrict__ edges,
                    int E, int chunk, int NB)
{
    __shared__ int cur[NBMAX];
    int tid = threadIdx.x, blk = blockIdx.x;
    for (int b = tid; b < NB; b += 256)
        cur[b] = bkt_ptr[b] + hist_g[b * NBLK + blk];
    __syncthreads();
    int s = blk * chunk, e = min(E, s + chunk);
    for (int i = s + tid; i < e; i += 256) {
        int r = rows[i];
        int b = r >> SHIFT;
        uint2 ed;
        ed.x = (unsigned)cols[i] | ((unsigned)(r & 63) << 20);
        ed.y = __float_as_uint(vals[i]);
        int p = atomicAdd(&cur[b], 1);
        edges[p] = ed;
    }
}

// ---------------- SpMM: per-bucket LDS fp32 accumulation ----------------
// h is PERMUTED: hperm[row*128 + 2l] = h[row][l], hperm[row*128 + 2l+1] = h[row][l+64]
// => lane l's half2 gather covers true cols {l, l+64}; ds_adds at stride 4B (conflict-free)
__global__ __launch_bounds__(256, 4)
void spmm_bucket(const int* __restrict__ bkt_ptr, const uint2* __restrict__ edges,
                 const _Float16* __restrict__ h, _Float16* __restrict__ temp, int N)
{
    __shared__ float acc[64 * 128];    // 32 KB, true-col order
    int tid = threadIdx.x;
    floatx4 z = {};
#pragma unroll
    for (int i = 0; i < 8; ++i)
        *(floatx4*)(acc + (tid + i * 256) * 4) = z;
    __syncthreads();

    int b = blockIdx.x;
    int s0 = bkt_ptr[b], e0 = bkt_ptr[b + 1];
    int wave = tid >> 6, lane = tid & 63;
    int len = e0 - s0;
    int per = (len + 3) >> 2;
    int ws_ = s0 + wave * per;
    int we_ = min(e0, ws_ + per);

    int i = ws_;
    for (; i + 3 < we_; i += 4) {
        uint2 e0v = edges[i], e1v = edges[i + 1], e2v = edges[i + 2], e3v = edges[i + 3];
        half2v v0 = *(const half2v*)(h + (size_t)(e0v.x & 0xFFFFF) * 128 + lane * 2);
        half2v v1 = *(const half2v*)(h + (size_t)(e1v.x & 0xFFFFF) * 128 + lane * 2);
        half2v v2 = *(const half2v*)(h + (size_t)(e2v.x & 0xFFFFF) * 128 + lane * 2);
        half2v v3 = *(const half2v*)(h + (size_t)(e3v.x & 0xFFFFF) * 128 + lane * 2);
        float a0 = __uint_as_float(e0v.y), a1 = __uint_as_float(e1v.y);
        float a2 = __uint_as_float(e2v.y), a3 = __uint_as_float(e3v.y);
        int r0 = e0v.x >> 20, r1 = e1v.x >> 20, r2 = e2v.x >> 20, r3 = e3v.x >> 20;
        unsafeAtomicAdd(&acc[r0 * 128 +      lane], a0 * (float)v0[0]);
        unsafeAtomicAdd(&acc[r0 * 128 + 64 + lane], a0 * (float)v0[1]);
        unsafeAtomicAdd(&acc[r1 * 128 +      lane], a1 * (float)v1[0]);
        unsafeAtomicAdd(&acc[r1 * 128 + 64 + lane], a1 * (float)v1[1]);
        unsafeAtomicAdd(&acc[r2 * 128 +      lane], a2 * (float)v2[0]);
        unsafeAtomicAdd(&acc[r2 * 128 + 64 + lane], a2 * (float)v2[1]);
        unsafeAtomicAdd(&acc[r3 * 128 +      lane], a3 * (float)v3[0]);
        unsafeAtomicAdd(&acc[r3 * 128 + 64 + lane], a3 * (float)v3[1]);
    }
    for (; i < we_; ++i) {
        uint2 ev = edges[i];
        half2v v = *(const half2v*)(h + (size_t)(ev.x & 0xFFFFF) * 128 + lane * 2);
        float a = __uint_as_float(ev.y);
        int r = ev.x >> 20;
        unsafeAtomicAdd(&acc[r * 128 +      lane], a * (float)v[0]);
        unsafeAtomicAdd(&acc[r * 128 + 64 + lane], a * (float)v[1]);
    }
    __syncthreads();

    // write rows [b*64, b*64+64) as f16 (true col order)
    int row0 = b << SHIFT;
#pragma unroll
    for (int i2 = 0; i2 < 4; ++i2) {
        int c = tid + i2 * 256;         // 1024 chunks of 8 halfs
        int row = c >> 4;
        int off = (c & 15) * 8;
        int grow = row0 + row;
        if (grow < N) {
            const float* src = acc + row * 128 + off;
            half8 hv;
#pragma unroll
            for (int j = 0; j < 8; ++j) hv[j] = (_Float16)src[j];
            *(half8*)(temp + (size_t)grow * 128 + off) = hv;
        }
    }
}

// ---------------- launcher ----------------
static inline size_t align256(size_t x) { return (x + 255) & ~(size_t)255; }

extern "C" void kernel_launch(void* const* d_in, const int* in_sizes, int n_in,
                              void* d_out, int out_size, void* d_ws, size_t ws_size,
                              hipStream_t stream)
{
    const float* AX        = (const float*)d_in[0];
    const int*   A_row     = (const int*)  d_in[1];
    const int*   A_col     = (const int*)  d_in[2];
    const float* A_val     = (const float*)d_in[3];
    const float* Wr_w      = (const float*)d_in[4];
    const float* Wr_b      = (const float*)d_in[5];
    const float* W_w       = (const float*)d_in[6];
    const float* W_b       = (const float*)d_in[7];
    const float* g_alpha   = (const float*)d_in[8];
    const float* act_alpha = (const float*)d_in[9];

    const int N = in_sizes[0] / 128;
    const int E = in_sizes[1];
    const int NB = (N + 63) >> SHIFT;            // 1563
    const int chunk = (E + NBLK - 1) / NBLK;     // 12500

    char* ws = (char*)d_ws;
    size_t off = 0;
    _Float16* hperm  = (_Float16*)(ws + off); off += align256((size_t)N * 128 * 2);
    _Float16* temp   = (_Float16*)(ws + off); off += align256((size_t)N * 128 * 2);
    uint2*    edges  = (uint2*)   (ws + off); off += align256((size_t)E * 8);
    int*      hist_g = (int*)     (ws + off); off += align256((size_t)NB * NBLK * 4);
    int*      tot    = (int*)     (ws + off); off += align256((size_t)NB * 4);
    int*      bkt_ptr= (int*)     (ws + off); off += align256((size_t)(NB + 1) * 4);
    (void)ws_size; (void)n_in; (void)out_size;

    const int gemm_grid = (N + 127) / 128;

    // h = prelu(AX @ Wr^T + br)  [f16, permuted col layout]
    gemm128_prelu<true, true, true><<<gemm_grid, 256, 0, stream>>>(AX, Wr_w, Wr_b, g_alpha, hperm, N);

    bucket_hist<<<NBLK, 256, 0, stream>>>(A_row, hist_g, E, chunk, NB);
    bucket_scan1<<<NB, NBLK, 0, stream>>>(hist_g, tot);
    bucket_scan2<<<1, 1024, 0, stream>>>(tot, bkt_ptr, NB, E);
    bucket_scatter<<<NBLK, 256, 0, stream>>>(A_row, A_col, A_val, bkt_ptr, hist_g, edges, E, chunk, NB);

    spmm_bucket<<<NB, 256, 0, stream>>>(bkt_ptr, edges, hperm, temp, N);

    // out = prelu(temp @ W^T + b)  [fp32]
    gemm128_prelu<false, false, false><<<gemm_grid, 256, 0, stream>>>(temp, W_w, W_b, act_alpha, d_out, N);
}

// Round 4
// 367.255 us; speedup vs baseline: 3.9089x; 3.9089x over previous
//
#include <hip/hip_runtime.h>
#include <stdint.h>

// GCN layer: out = prelu(W @ segsum(A_val * h[A_col] -> A_row) + b, act_a)
//            h   = prelu(Wr @ AX + br, g_a)
// R4: f16 MFMA GEMMs; SpMM = radix pass into 3125 buckets of 32 rows
// (dense block-contiguous writes), then per-bucket LDS COUNTING SORT by row
// + per-wave REGISTER accumulation (8 rows/wave, 2 f32/lane).
// R3 lesson: fp32 atomicAdd on LDS is pathological (~230 cyc/op, 1197us).
// Only int LDS atomics (native ds_add) are used here.

typedef _Float16 half8 __attribute__((ext_vector_type(8)));
typedef _Float16 half4 __attribute__((ext_vector_type(4)));
typedef _Float16 half2v __attribute__((ext_vector_type(2)));
typedef float floatx4 __attribute__((ext_vector_type(4)));

#define LDK 136        // GEMM LDS row stride in halfs: 128 + 8
#define SHIFT 5        // 32 rows per bucket
#define NBMAX 3200     // >= ceil(100000/32) = 3125
#define NBLK 64        // hist/scatter chunks: E/64/3125 ~= 8 edges per (blk,bucket) = 64B line
#define CAP 1024       // LDS edge capacity per sort chunk (max bucket ~590 expected)

// ---------------- GEMM: out = prelu(X @ W^T + b) ----------------
template<bool IN_F32, bool OUT_F16>
__global__ __launch_bounds__(256, 2)
void gemm128_prelu(const void* __restrict__ Xv, const float* __restrict__ W,
                   const float* __restrict__ bias, const float* __restrict__ alpha_p,
                   void* __restrict__ outv, int N)
{
    __shared__ _Float16 Xs[128 * LDK];
    __shared__ _Float16 Ws[128 * LDK];
    const int tid = threadIdx.x;
    const int bm  = blockIdx.x * 128;
    const float alpha = *alpha_p;

#pragma unroll
    for (int i = 0; i < 16; ++i) {
        int c   = tid + i * 256;
        int row = c >> 5;
        int coff = (c & 31) * 4;
        float4 f = *(const float4*)(W + row * 128 + coff);
        half4 hv = { (_Float16)f.x, (_Float16)f.y, (_Float16)f.z, (_Float16)f.w };
        *(half4*)(&Ws[row * LDK + coff]) = hv;
    }
    if (IN_F32) {
        const float* X = (const float*)Xv;
#pragma unroll
        for (int i = 0; i < 16; ++i) {
            int c   = tid + i * 256;
            int row = c >> 5;
            int coff = (c & 31) * 4;
            int grow = bm + row;
            half4 hv = {};
            if (grow < N) {
                float4 f = *(const float4*)(X + (size_t)grow * 128 + coff);
                hv[0] = (_Float16)f.x; hv[1] = (_Float16)f.y;
                hv[2] = (_Float16)f.z; hv[3] = (_Float16)f.w;
            }
            *(half4*)(&Xs[row * LDK + coff]) = hv;
        }
    } else {
        const _Float16* X = (const _Float16*)Xv;
#pragma unroll
        for (int i = 0; i < 8; ++i) {
            int c   = tid + i * 256;
            int row = c >> 4;
            int coff = (c & 15) * 8;
            int grow = bm + row;
            half8 hv = {};
            if (grow < N) hv = *(const half8*)(X + (size_t)grow * 128 + coff);
            *(half8*)(&Xs[row * LDK + coff]) = hv;
        }
    }
    __syncthreads();

    const int wave = tid >> 6;
    const int lane = tid & 63;
    const int l15  = lane & 15;
    const int quad = lane >> 4;

    floatx4 acc[2][8] = {};
#pragma unroll
    for (int k0 = 0; k0 < 128; k0 += 32) {
        half8 a0 = *(const half8*)(&Xs[(wave * 32 +      l15) * LDK + k0 + quad * 8]);
        half8 a1 = *(const half8*)(&Xs[(wave * 32 + 16 + l15) * LDK + k0 + quad * 8]);
        half8 b[8];
#pragma unroll
        for (int n = 0; n < 8; ++n)
            b[n] = *(const half8*)(&Ws[(n * 16 + l15) * LDK + k0 + quad * 8]);
#pragma unroll
        for (int n = 0; n < 8; ++n) {
            acc[0][n] = __builtin_amdgcn_mfma_f32_16x16x32_f16(a0, b[n], acc[0][n], 0, 0, 0);
            acc[1][n] = __builtin_amdgcn_mfma_f32_16x16x32_f16(a1, b[n], acc[1][n], 0, 0, 0);
        }
    }

#pragma unroll
    for (int mt = 0; mt < 2; ++mt) {
#pragma unroll
        for (int n = 0; n < 8; ++n) {
#pragma unroll
            for (int r = 0; r < 4; ++r) {
                int row = bm + wave * 32 + mt * 16 + quad * 4 + r;
                int col = n * 16 + l15;
                if (row < N) {
                    float v = acc[mt][n][r] + bias[col];
                    v = (v >= 0.f) ? v : alpha * v;
                    if (OUT_F16) ((_Float16*)outv)[(size_t)row * 128 + col] = (_Float16)v;
                    else         ((float*)outv)[(size_t)row * 128 + col]    = v;
                }
            }
        }
    }
}

// ---------------- bucket radix pass ----------------
// hist_g[bucket*NBLK + blk] = #edges of bucket in chunk blk
__global__ __launch_bounds__(256)
void bucket_hist(const int* __restrict__ rows, int* __restrict__ hist_g,
                 int E, int chunk, int NB)
{
    __shared__ int lh[NBMAX];
    int tid = threadIdx.x, blk = blockIdx.x;
    for (int i = tid; i < NB; i += 256) lh[i] = 0;
    __syncthreads();
    int s = blk * chunk, e = min(E, s + chunk);
    for (int i = s + tid; i < e; i += 256)
        atomicAdd(&lh[rows[i] >> SHIFT], 1);
    __syncthreads();
    for (int b = tid; b < NB; b += 256)
        hist_g[b * NBLK + blk] = lh[b];
}

// per-bucket exclusive scan over NBLK block-counts (in place) + bucket total
__global__ __launch_bounds__(NBLK)
void bucket_scan1(int* __restrict__ hist_g, int* __restrict__ tot)
{
    __shared__ int sd[NBLK];
    int b = blockIdx.x, t = threadIdx.x;
    int v = hist_g[b * NBLK + t];
    sd[t] = v;
    __syncthreads();
    for (int off = 1; off < NBLK; off <<= 1) {
        int x = (t >= off) ? sd[t - off] : 0;
        __syncthreads();
        sd[t] += x;
        __syncthreads();
    }
    hist_g[b * NBLK + t] = sd[t] - v;   // exclusive
    if (t == NBLK - 1) tot[b] = sd[t];
}

// exclusive scan of bucket totals -> bkt_ptr[0..NB]. 1 block x 1024, 4/thread.
__global__ __launch_bounds__(1024)
void bucket_scan2(const int* __restrict__ tot, int* __restrict__ bkt_ptr, int NB, int E)
{
    __shared__ int sd[1024];
    int t = threadIdx.x;
    int v[4]; int s = 0;
#pragma unroll
    for (int j = 0; j < 4; ++j) {
        int idx = t * 4 + j;
        v[j] = (idx < NB) ? tot[idx] : 0;
        s += v[j];
    }
    sd[t] = s;
    __syncthreads();
    for (int off = 1; off < 1024; off <<= 1) {
        int x = (t >= off) ? sd[t - off] : 0;
        __syncthreads();
        sd[t] += x;
        __syncthreads();
    }
    int base = (t == 0) ? 0 : sd[t - 1];
#pragma unroll
    for (int j = 0; j < 4; ++j) {
        int idx = t * 4 + j;
        if (idx < NB) { bkt_ptr[idx] = base; base += v[j]; }
    }
    if (t == 0) bkt_ptr[NB] = E;
}

// scatter edges into bucket-contiguous storage; packed (col | rloc<<20, valbits)
__global__ __launch_bounds__(256)
void bucket_scatter(const int* __restrict__ rows, const int* __restrict__ cols,
                    const float* __restrict__ vals, const int* __restrict__ bkt_ptr,
                    const int* __restrict__ hist_g, uint2* __restrict__ edges,
                    int E, int chunk, int NB)
{
    __shared__ int cur[NBMAX];
    int tid = threadIdx.x, blk = blockIdx.x;
    for (int b = tid; b < NB; b += 256)
        cur[b] = bkt_ptr[b] + hist_g[b * NBLK + blk];
    __syncthreads();
    int s = blk * chunk, e = min(E, s + chunk);
    for (int i = s + tid; i < e; i += 256) {
        int r = rows[i];
        int b = r >> SHIFT;
        uint2 ed;
        ed.x = (unsigned)cols[i] | ((unsigned)(r & 31) << 20);
        ed.y = __float_as_uint(vals[i]);
        int p = atomicAdd(&cur[b], 1);
        edges[p] = ed;
    }
}

// ---------------- SpMM: per-bucket counting sort + register accumulation ----
// block = 256 thr = 4 waves; bucket = 32 rows; wave w owns rows [w*8, w*8+8).
// lane l accumulates true cols {2l, 2l+1} in 2 fp32 regs per row.
__global__ __launch_bounds__(256)
void spmm_sort(const int* __restrict__ bkt_ptr, const uint2* __restrict__ edges,
               const _Float16* __restrict__ h, _Float16* __restrict__ temp, int N)
{
    __shared__ uint2 eL[CAP];       // staged raw edges
    __shared__ uint2 eS[CAP];       // row-sorted edges
    __shared__ int bins[32], cur[32], startS[33];

    const int tid  = threadIdx.x;
    const int wave = tid >> 6;
    const int lane = tid & 63;
    const int b    = blockIdx.x;
    const int s0   = bkt_ptr[b], e0 = bkt_ptr[b + 1];

    float acc[8][2] = {};   // 8 rows per wave, 2 cols per lane

    for (int base = s0; base < e0; base += CAP) {
        const int n = min(CAP, e0 - base);
        if (tid < 32) bins[tid] = 0;
        __syncthreads();
        for (int i = tid; i < n; i += 256) {
            uint2 ed = edges[base + i];
            eL[i] = ed;
            atomicAdd(&bins[ed.x >> 20], 1);
        }
        __syncthreads();
        if (tid == 0) {
            int a = 0;
#pragma unroll
            for (int r = 0; r < 32; ++r) { startS[r] = a; a += bins[r]; }
            startS[32] = a;
        }
        __syncthreads();
        if (tid < 32) cur[tid] = startS[tid];
        __syncthreads();
        for (int i = tid; i < n; i += 256) {
            uint2 ed = eL[i];
            int p = atomicAdd(&cur[ed.x >> 20], 1);
            eS[p] = ed;
        }
        __syncthreads();

#pragma unroll
        for (int j = 0; j < 8; ++j) {
            int r  = wave * 8 + j;
            int rs = startS[r], re = startS[r + 1];
            float a0r = acc[j][0], a1r = acc[j][1];
            int i = rs;
            for (; i + 3 < re; i += 4) {
                uint2 e0v = eS[i], e1v = eS[i + 1], e2v = eS[i + 2], e3v = eS[i + 3];
                half2v v0 = *(const half2v*)(h + (size_t)(e0v.x & 0xFFFFF) * 128 + lane * 2);
                half2v v1 = *(const half2v*)(h + (size_t)(e1v.x & 0xFFFFF) * 128 + lane * 2);
                half2v v2 = *(const half2v*)(h + (size_t)(e2v.x & 0xFFFFF) * 128 + lane * 2);
                half2v v3 = *(const half2v*)(h + (size_t)(e3v.x & 0xFFFFF) * 128 + lane * 2);
                float w0 = __uint_as_float(e0v.y), w1 = __uint_as_float(e1v.y);
                float w2 = __uint_as_float(e2v.y), w3 = __uint_as_float(e3v.y);
                a0r += w0 * (float)v0[0]; a1r += w0 * (float)v0[1];
                a0r += w1 * (float)v1[0]; a1r += w1 * (float)v1[1];
                a0r += w2 * (float)v2[0]; a1r += w2 * (float)v2[1];
                a0r += w3 * (float)v3[0]; a1r += w3 * (float)v3[1];
            }
            for (; i < re; ++i) {
                uint2 ev = eS[i];
                half2v v = *(const half2v*)(h + (size_t)(ev.x & 0xFFFFF) * 128 + lane * 2);
                float w = __uint_as_float(ev.y);
                a0r += w * (float)v[0]; a1r += w * (float)v[1];
            }
            acc[j][0] = a0r; acc[j][1] = a1r;
        }
        __syncthreads();   // protect eL/eS before next chunk
    }

    const int row0 = (b << SHIFT) + wave * 8;
#pragma unroll
    for (int j = 0; j < 8; ++j) {
        int grow = row0 + j;
        if (grow < N) {
            half2v o = { (_Float16)acc[j][0], (_Float16)acc[j][1] };
            *(half2v*)(temp + (size_t)grow * 128 + lane * 2) = o;
        }
    }
}

// ---------------- launcher ----------------
static inline size_t align256(size_t x) { return (x + 255) & ~(size_t)255; }

extern "C" void kernel_launch(void* const* d_in, const int* in_sizes, int n_in,
                              void* d_out, int out_size, void* d_ws, size_t ws_size,
                              hipStream_t stream)
{
    const float* AX        = (const float*)d_in[0];
    const int*   A_row     = (const int*)  d_in[1];
    const int*   A_col     = (const int*)  d_in[2];
    const float* A_val     = (const float*)d_in[3];
    const float* Wr_w      = (const float*)d_in[4];
    const float* Wr_b      = (const float*)d_in[5];
    const float* W_w       = (const float*)d_in[6];
    const float* W_b       = (const float*)d_in[7];
    const float* g_alpha   = (const float*)d_in[8];
    const float* act_alpha = (const float*)d_in[9];

    const int N = in_sizes[0] / 128;
    const int E = in_sizes[1];
    const int NB = (N + 31) >> SHIFT;            // 3125
    const int chunk = (E + NBLK - 1) / NBLK;     // 25000

    char* ws = (char*)d_ws;
    size_t off = 0;
    _Float16* h      = (_Float16*)(ws + off); off += align256((size_t)N * 128 * 2);
    _Float16* temp   = (_Float16*)(ws + off); off += align256((size_t)N * 128 * 2);
    uint2*    edges  = (uint2*)   (ws + off); off += align256((size_t)E * 8);
    int*      hist_g = (int*)     (ws + off); off += align256((size_t)NB * NBLK * 4);
    int*      tot    = (int*)     (ws + off); off += align256((size_t)NB * 4);
    int*      bkt_ptr= (int*)     (ws + off); off += align256((size_t)(NB + 1) * 4);
    (void)ws_size; (void)n_in; (void)out_size;

    const int gemm_grid = (N + 127) / 128;

    // h = prelu(AX @ Wr^T + br)  [f16]
    gemm128_prelu<true, true><<<gemm_grid, 256, 0, stream>>>(AX, Wr_w, Wr_b, g_alpha, h, N);

    bucket_hist<<<NBLK, 256, 0, stream>>>(A_row, hist_g, E, chunk, NB);
    bucket_scan1<<<NB, NBLK, 0, stream>>>(hist_g, tot);
    bucket_scan2<<<1, 1024, 0, stream>>>(tot, bkt_ptr, NB, E);
    bucket_scatter<<<NBLK, 256, 0, stream>>>(A_row, A_col, A_val, bkt_ptr, hist_g, edges, E, chunk, NB);

    spmm_sort<<<NB, 256, 0, stream>>>(bkt_ptr, edges, h, temp, N);

    // out = prelu(temp @ W^T + b)  [fp32]
    gemm128_prelu<false, false><<<gemm_grid, 256, 0, stream>>>(temp, W_w, W_b, act_alpha, d_out, N);
}

// Round 5
// 315.643 us; speedup vs baseline: 4.5481x; 1.1635x over previous
//
#include <hip/hip_runtime.h>
#include <stdint.h>

// GCN layer: out = prelu(W @ segsum(A_val * h[A_col] -> A_row) + b, act_a)
//            h   = prelu(Wr @ AX + br, g_a)
// R5: same structure as R4 (radix buckets of 32 rows -> per-bucket LDS
// counting sort -> register accumulation), but hist/scatter now use
// NBLK=128 chunks x 1024 threads (R4: 64x256 = 2.4% occupancy, scatter was
// parallelism-limited at 0.64 TB/s vs R2's 1.5 TB/s full-grid rate).
// R3 lesson: NO fp32 atomics anywhere (LDS fp32 atomicAdd ~230cyc/op).

typedef _Float16 half8 __attribute__((ext_vector_type(8)));
typedef _Float16 half4 __attribute__((ext_vector_type(4)));
typedef _Float16 half2v __attribute__((ext_vector_type(2)));
typedef float floatx4 __attribute__((ext_vector_type(4)));

#define LDK 136        // GEMM LDS row stride in halfs: 128 + 8
#define SHIFT 5        // 32 rows per bucket
#define NBMAX 3200     // >= ceil(100000/32) = 3125
#define NBLK 128       // hist/scatter chunks
#define SCT 1024       // hist/scatter threads per block
#define CAP 1024       // LDS edge capacity per sort chunk (max bucket ~590 expected)

// ---------------- GEMM: out = prelu(X @ W^T + b) ----------------
template<bool IN_F32, bool OUT_F16>
__global__ __launch_bounds__(256, 2)
void gemm128_prelu(const void* __restrict__ Xv, const float* __restrict__ W,
                   const float* __restrict__ bias, const float* __restrict__ alpha_p,
                   void* __restrict__ outv, int N)
{
    __shared__ _Float16 Xs[128 * LDK];
    __shared__ _Float16 Ws[128 * LDK];
    const int tid = threadIdx.x;
    const int bm  = blockIdx.x * 128;
    const float alpha = *alpha_p;

#pragma unroll
    for (int i = 0; i < 16; ++i) {
        int c   = tid + i * 256;
        int row = c >> 5;
        int coff = (c & 31) * 4;
        float4 f = *(const float4*)(W + row * 128 + coff);
        half4 hv = { (_Float16)f.x, (_Float16)f.y, (_Float16)f.z, (_Float16)f.w };
        *(half4*)(&Ws[row * LDK + coff]) = hv;
    }
    if (IN_F32) {
        const float* X = (const float*)Xv;
#pragma unroll
        for (int i = 0; i < 16; ++i) {
            int c   = tid + i * 256;
            int row = c >> 5;
            int coff = (c & 31) * 4;
            int grow = bm + row;
            half4 hv = {};
            if (grow < N) {
                float4 f = *(const float4*)(X + (size_t)grow * 128 + coff);
                hv[0] = (_Float16)f.x; hv[1] = (_Float16)f.y;
                hv[2] = (_Float16)f.z; hv[3] = (_Float16)f.w;
            }
            *(half4*)(&Xs[row * LDK + coff]) = hv;
        }
    } else {
        const _Float16* X = (const _Float16*)Xv;
#pragma unroll
        for (int i = 0; i < 8; ++i) {
            int c   = tid + i * 256;
            int row = c >> 4;
            int coff = (c & 15) * 8;
            int grow = bm + row;
            half8 hv = {};
            if (grow < N) hv = *(const half8*)(X + (size_t)grow * 128 + coff);
            *(half8*)(&Xs[row * LDK + coff]) = hv;
        }
    }
    __syncthreads();

    const int wave = tid >> 6;
    const int lane = tid & 63;
    const int l15  = lane & 15;
    const int quad = lane >> 4;

    floatx4 acc[2][8] = {};
#pragma unroll
    for (int k0 = 0; k0 < 128; k0 += 32) {
        half8 a0 = *(const half8*)(&Xs[(wave * 32 +      l15) * LDK + k0 + quad * 8]);
        half8 a1 = *(const half8*)(&Xs[(wave * 32 + 16 + l15) * LDK + k0 + quad * 8]);
        half8 b[8];
#pragma unroll
        for (int n = 0; n < 8; ++n)
            b[n] = *(const half8*)(&Ws[(n * 16 + l15) * LDK + k0 + quad * 8]);
#pragma unroll
        for (int n = 0; n < 8; ++n) {
            acc[0][n] = __builtin_amdgcn_mfma_f32_16x16x32_f16(a0, b[n], acc[0][n], 0, 0, 0);
            acc[1][n] = __builtin_amdgcn_mfma_f32_16x16x32_f16(a1, b[n], acc[1][n], 0, 0, 0);
        }
    }

#pragma unroll
    for (int mt = 0; mt < 2; ++mt) {
#pragma unroll
        for (int n = 0; n < 8; ++n) {
#pragma unroll
            for (int r = 0; r < 4; ++r) {
                int row = bm + wave * 32 + mt * 16 + quad * 4 + r;
                int col = n * 16 + l15;
                if (row < N) {
                    float v = acc[mt][n][r] + bias[col];
                    v = (v >= 0.f) ? v : alpha * v;
                    if (OUT_F16) ((_Float16*)outv)[(size_t)row * 128 + col] = (_Float16)v;
                    else         ((float*)outv)[(size_t)row * 128 + col]    = v;
                }
            }
        }
    }
}

// ---------------- bucket radix pass ----------------
// hist_g[bucket*NBLK + blk] = #edges of bucket in chunk blk
__global__ __launch_bounds__(SCT)
void bucket_hist(const int* __restrict__ rows, int* __restrict__ hist_g,
                 int E, int chunk, int NB)
{
    __shared__ int lh[NBMAX];
    int tid = threadIdx.x, blk = blockIdx.x;
    for (int i = tid; i < NB; i += SCT) lh[i] = 0;
    __syncthreads();
    int s = blk * chunk, e = min(E, s + chunk);
    for (int i = s + tid; i < e; i += SCT)
        atomicAdd(&lh[rows[i] >> SHIFT], 1);
    __syncthreads();
    for (int b = tid; b < NB; b += SCT)
        hist_g[b * NBLK + blk] = lh[b];
}

// per-bucket exclusive scan over NBLK block-counts (in place) + bucket total
__global__ __launch_bounds__(NBLK)
void bucket_scan1(int* __restrict__ hist_g, int* __restrict__ tot)
{
    __shared__ int sd[NBLK];
    int b = blockIdx.x, t = threadIdx.x;
    int v = hist_g[b * NBLK + t];
    sd[t] = v;
    __syncthreads();
    for (int off = 1; off < NBLK; off <<= 1) {
        int x = (t >= off) ? sd[t - off] : 0;
        __syncthreads();
        sd[t] += x;
        __syncthreads();
    }
    hist_g[b * NBLK + t] = sd[t] - v;   // exclusive
    if (t == NBLK - 1) tot[b] = sd[t];
}

// exclusive scan of bucket totals -> bkt_ptr[0..NB]. 1 block x 1024, 4/thread.
__global__ __launch_bounds__(1024)
void bucket_scan2(const int* __restrict__ tot, int* __restrict__ bkt_ptr, int NB, int E)
{
    __shared__ int sd[1024];
    int t = threadIdx.x;
    int v[4]; int s = 0;
#pragma unroll
    for (int j = 0; j < 4; ++j) {
        int idx = t * 4 + j;
        v[j] = (idx < NB) ? tot[idx] : 0;
        s += v[j];
    }
    sd[t] = s;
    __syncthreads();
    for (int off = 1; off < 1024; off <<= 1) {
        int x = (t >= off) ? sd[t - off] : 0;
        __syncthreads();
        sd[t] += x;
        __syncthreads();
    }
    int base = (t == 0) ? 0 : sd[t - 1];
#pragma unroll
    for (int j = 0; j < 4; ++j) {
        int idx = t * 4 + j;
        if (idx < NB) { bkt_ptr[idx] = base; base += v[j]; }
    }
    if (t == 0) bkt_ptr[NB] = E;
}

// scatter edges into bucket-contiguous storage; packed (col | rloc<<20, valbits)
__global__ __launch_bounds__(SCT)
void bucket_scatter(const int* __restrict__ rows, const int* __restrict__ cols,
                    const float* __restrict__ vals, const int* __restrict__ bkt_ptr,
                    const int* __restrict__ hist_g, uint2* __restrict__ edges,
                    int E, int chunk, int NB)
{
    __shared__ int cur[NBMAX];
    int tid = threadIdx.x, blk = blockIdx.x;
    for (int b = tid; b < NB; b += SCT)
        cur[b] = bkt_ptr[b] + hist_g[b * NBLK + blk];
    __syncthreads();
    int s = blk * chunk, e = min(E, s + chunk);
    for (int i = s + tid; i < e; i += SCT) {
        int r = rows[i];
        int b = r >> SHIFT;
        uint2 ed;
        ed.x = (unsigned)cols[i] | ((unsigned)(r & 31) << 20);
        ed.y = __float_as_uint(vals[i]);
        int p = atomicAdd(&cur[b], 1);
        edges[p] = ed;
    }
}

// ---------------- SpMM: per-bucket counting sort + register accumulation ----
// block = 256 thr = 4 waves; bucket = 32 rows; wave w owns rows [w*8, w*8+8).
// lane l accumulates true cols {2l, 2l+1} in 2 fp32 regs per row.
__global__ __launch_bounds__(256)
void spmm_sort(const int* __restrict__ bkt_ptr, const uint2* __restrict__ edges,
               const _Float16* __restrict__ h, _Float16* __restrict__ temp, int N)
{
    __shared__ uint2 eL[CAP];       // staged raw edges
    __shared__ uint2 eS[CAP];       // row-sorted edges
    __shared__ int bins[32], cur[32], startS[33];

    const int tid  = threadIdx.x;
    const int wave = tid >> 6;
    const int lane = tid & 63;
    const int b    = blockIdx.x;
    const int s0   = bkt_ptr[b], e0 = bkt_ptr[b + 1];

    float acc[8][2] = {};   // 8 rows per wave, 2 cols per lane

    for (int base = s0; base < e0; base += CAP) {
        const int n = min(CAP, e0 - base);
        if (tid < 32) bins[tid] = 0;
        __syncthreads();
        for (int i = tid; i < n; i += 256) {
            uint2 ed = edges[base + i];
            eL[i] = ed;
            atomicAdd(&bins[ed.x >> 20], 1);
        }
        __syncthreads();
        if (tid == 0) {
            int a = 0;
#pragma unroll
            for (int r = 0; r < 32; ++r) { startS[r] = a; a += bins[r]; }
            startS[32] = a;
        }
        __syncthreads();
        if (tid < 32) cur[tid] = startS[tid];
        __syncthreads();
        for (int i = tid; i < n; i += 256) {
            uint2 ed = eL[i];
            int p = atomicAdd(&cur[ed.x >> 20], 1);
            eS[p] = ed;
        }
        __syncthreads();

#pragma unroll
        for (int j = 0; j < 8; ++j) {
            int r  = wave * 8 + j;
            int rs = startS[r], re = startS[r + 1];
            float a0r = acc[j][0], a1r = acc[j][1];
            int i = rs;
            for (; i + 3 < re; i += 4) {
                uint2 e0v = eS[i], e1v = eS[i + 1], e2v = eS[i + 2], e3v = eS[i + 3];
                half2v v0 = *(const half2v*)(h + (size_t)(e0v.x & 0xFFFFF) * 128 + lane * 2);
                half2v v1 = *(const half2v*)(h + (size_t)(e1v.x & 0xFFFFF) * 128 + lane * 2);
                half2v v2 = *(const half2v*)(h + (size_t)(e2v.x & 0xFFFFF) * 128 + lane * 2);
                half2v v3 = *(const half2v*)(h + (size_t)(e3v.x & 0xFFFFF) * 128 + lane * 2);
                float w0 = __uint_as_float(e0v.y), w1 = __uint_as_float(e1v.y);
                float w2 = __uint_as_float(e2v.y), w3 = __uint_as_float(e3v.y);
                a0r += w0 * (float)v0[0]; a1r += w0 * (float)v0[1];
                a0r += w1 * (float)v1[0]; a1r += w1 * (float)v1[1];
                a0r += w2 * (float)v2[0]; a1r += w2 * (float)v2[1];
                a0r += w3 * (float)v3[0]; a1r += w3 * (float)v3[1];
            }
            for (; i < re; ++i) {
                uint2 ev = eS[i];
                half2v v = *(const half2v*)(h + (size_t)(ev.x & 0xFFFFF) * 128 + lane * 2);
                float w = __uint_as_float(ev.y);
                a0r += w * (float)v[0]; a1r += w * (float)v[1];
            }
            acc[j][0] = a0r; acc[j][1] = a1r;
        }
        __syncthreads();   // protect eL/eS before next chunk
    }

    const int row0 = (b << SHIFT) + wave * 8;
#pragma unroll
    for (int j = 0; j < 8; ++j) {
        int grow = row0 + j;
        if (grow < N) {
            half2v o = { (_Float16)acc[j][0], (_Float16)acc[j][1] };
            *(half2v*)(temp + (size_t)grow * 128 + lane * 2) = o;
        }
    }
}

// ---------------- launcher ----------------
static inline size_t align256(size_t x) { return (x + 255) & ~(size_t)255; }

extern "C" void kernel_launch(void* const* d_in, const int* in_sizes, int n_in,
                              void* d_out, int out_size, void* d_ws, size_t ws_size,
                              hipStream_t stream)
{
    const float* AX        = (const float*)d_in[0];
    const int*   A_row     = (const int*)  d_in[1];
    const int*   A_col     = (const int*)  d_in[2];
    const float* A_val     = (const float*)d_in[3];
    const float* Wr_w      = (const float*)d_in[4];
    const float* Wr_b      = (const float*)d_in[5];
    const float* W_w       = (const float*)d_in[6];
    const float* W_b       = (const float*)d_in[7];
    const float* g_alpha   = (const float*)d_in[8];
    const float* act_alpha = (const float*)d_in[9];

    const int N = in_sizes[0] / 128;
    const int E = in_sizes[1];
    const int NB = (N + 31) >> SHIFT;            // 3125
    const int chunk = (E + NBLK - 1) / NBLK;     // 12500

    char* ws = (char*)d_ws;
    size_t off = 0;
    _Float16* h      = (_Float16*)(ws + off); off += align256((size_t)N * 128 * 2);
    _Float16* temp   = (_Float16*)(ws + off); off += align256((size_t)N * 128 * 2);
    uint2*    edges  = (uint2*)   (ws + off); off += align256((size_t)E * 8);
    int*      hist_g = (int*)     (ws + off); off += align256((size_t)NB * NBLK * 4);
    int*      tot    = (int*)     (ws + off); off += align256((size_t)NB * 4);
    int*      bkt_ptr= (int*)     (ws + off); off += align256((size_t)(NB + 1) * 4);
    (void)ws_size; (void)n_in; (void)out_size;

    const int gemm_grid = (N + 127) / 128;

    // h = prelu(AX @ Wr^T + br)  [f16]
    gemm128_prelu<true, true><<<gemm_grid, 256, 0, stream>>>(AX, Wr_w, Wr_b, g_alpha, h, N);

    bucket_hist<<<NBLK, SCT, 0, stream>>>(A_row, hist_g, E, chunk, NB);
    bucket_scan1<<<NB, NBLK, 0, stream>>>(hist_g, tot);
    bucket_scan2<<<1, 1024, 0, stream>>>(tot, bkt_ptr, NB, E);
    bucket_scatter<<<NBLK, SCT, 0, stream>>>(A_row, A_col, A_val, bkt_ptr, hist_g, edges, E, chunk, NB);

    spmm_sort<<<NB, 256, 0, stream>>>(bkt_ptr, edges, h, temp, N);

    // out = prelu(temp @ W^T + b)  [fp32]
    gemm128_prelu<false, false><<<gemm_grid, 256, 0, stream>>>(temp, W_w, W_b, act_alpha, d_out, N);
}

// Round 6
// 306.673 us; speedup vs baseline: 4.6811x; 1.0292x over previous
//
#include <hip/hip_runtime.h>
#include <stdint.h>

// GCN layer: out = prelu(W @ segsum(A_val * h[A_col] -> A_row) + b, act_a)
//            h   = prelu(Wr @ AX + br, g_a)
// R6: GEMM2 is FUSED into the SpMM kernel: per-bucket 32x128 temp tile goes
// to LDS, 16 MFMAs/wave vs f16 W (pre-converted inside scan2's kernel),
// bias+prelu, fp32 out written directly. 7 -> 6 dispatches, temp buffer gone.
// R5 evidence: spmm gather replicates h (25.6MB) across all 8 XCD L2s
// (FETCH 176MB ~ 7x h) at ~3 TB/s L2-miss BW -> latency/BW hybrid; unroll-8
// doubles outstanding loads. R3 lesson: no fp32 atomics anywhere.

typedef _Float16 half8 __attribute__((ext_vector_type(8)));
typedef _Float16 half4 __attribute__((ext_vector_type(4)));
typedef _Float16 half2v __attribute__((ext_vector_type(2)));
typedef float floatx4 __attribute__((ext_vector_type(4)));

#define LDK 136        // GEMM LDS row stride in halfs: 128 + 8
#define SHIFT 5        // 32 rows per bucket
#define NBMAX 3200     // >= ceil(100000/32) = 3125
#define NBLK 128       // hist/scatter chunks
#define SCT 1024       // hist/scatter threads per block
#define CAP 1024       // LDS edge capacity per sort chunk (max bucket ~650 expected)

// ---------------- GEMM1: h = prelu(AX @ Wr^T + br) [f16 out] ----------------
__global__ __launch_bounds__(256, 2)
void gemm128_prelu(const float* __restrict__ X, const float* __restrict__ W,
                   const float* __restrict__ bias, const float* __restrict__ alpha_p,
                   _Float16* __restrict__ out, int N)
{
    __shared__ _Float16 Xs[128 * LDK];
    __shared__ _Float16 Ws[128 * LDK];
    const int tid = threadIdx.x;
    const int bm  = blockIdx.x * 128;
    const float alpha = *alpha_p;

#pragma unroll
    for (int i = 0; i < 16; ++i) {
        int c   = tid + i * 256;
        int row = c >> 5;
        int coff = (c & 31) * 4;
        float4 f = *(const float4*)(W + row * 128 + coff);
        half4 hv = { (_Float16)f.x, (_Float16)f.y, (_Float16)f.z, (_Float16)f.w };
        *(half4*)(&Ws[row * LDK + coff]) = hv;
    }
#pragma unroll
    for (int i = 0; i < 16; ++i) {
        int c   = tid + i * 256;
        int row = c >> 5;
        int coff = (c & 31) * 4;
        int grow = bm + row;
        half4 hv = {};
        if (grow < N) {
            float4 f = *(const float4*)(X + (size_t)grow * 128 + coff);
            hv[0] = (_Float16)f.x; hv[1] = (_Float16)f.y;
            hv[2] = (_Float16)f.z; hv[3] = (_Float16)f.w;
        }
        *(half4*)(&Xs[row * LDK + coff]) = hv;
    }
    __syncthreads();

    const int wave = tid >> 6;
    const int lane = tid & 63;
    const int l15  = lane & 15;
    const int quad = lane >> 4;

    floatx4 acc[2][8] = {};
#pragma unroll
    for (int k0 = 0; k0 < 128; k0 += 32) {
        half8 a0 = *(const half8*)(&Xs[(wave * 32 +      l15) * LDK + k0 + quad * 8]);
        half8 a1 = *(const half8*)(&Xs[(wave * 32 + 16 + l15) * LDK + k0 + quad * 8]);
        half8 b[8];
#pragma unroll
        for (int n = 0; n < 8; ++n)
            b[n] = *(const half8*)(&Ws[(n * 16 + l15) * LDK + k0 + quad * 8]);
#pragma unroll
        for (int n = 0; n < 8; ++n) {
            acc[0][n] = __builtin_amdgcn_mfma_f32_16x16x32_f16(a0, b[n], acc[0][n], 0, 0, 0);
            acc[1][n] = __builtin_amdgcn_mfma_f32_16x16x32_f16(a1, b[n], acc[1][n], 0, 0, 0);
        }
    }

#pragma unroll
    for (int mt = 0; mt < 2; ++mt) {
#pragma unroll
        for (int n = 0; n < 8; ++n) {
#pragma unroll
            for (int r = 0; r < 4; ++r) {
                int row = bm + wave * 32 + mt * 16 + quad * 4 + r;
                int col = n * 16 + l15;
                if (row < N) {
                    float v = acc[mt][n][r] + bias[col];
                    v = (v >= 0.f) ? v : alpha * v;
                    out[(size_t)row * 128 + col] = (_Float16)v;
                }
            }
        }
    }
}

// ---------------- bucket radix pass ----------------
__global__ __launch_bounds__(SCT)
void bucket_hist(const int* __restrict__ rows, int* __restrict__ hist_g,
                 int E, int chunk, int NB)
{
    __shared__ int lh[NBMAX];
    int tid = threadIdx.x, blk = blockIdx.x;
    for (int i = tid; i < NB; i += SCT) lh[i] = 0;
    __syncthreads();
    int s = blk * chunk, e = min(E, s + chunk);
    for (int i = s + tid; i < e; i += SCT)
        atomicAdd(&lh[rows[i] >> SHIFT], 1);
    __syncthreads();
    for (int b = tid; b < NB; b += SCT)
        hist_g[b * NBLK + blk] = lh[b];
}

// per-bucket exclusive scan over NBLK block-counts (in place) + bucket total
__global__ __launch_bounds__(NBLK)
void bucket_scan1(int* __restrict__ hist_g, int* __restrict__ tot)
{
    __shared__ int sd[NBLK];
    int b = blockIdx.x, t = threadIdx.x;
    int v = hist_g[b * NBLK + t];
    sd[t] = v;
    __syncthreads();
    for (int off = 1; off < NBLK; off <<= 1) {
        int x = (t >= off) ? sd[t - off] : 0;
        __syncthreads();
        sd[t] += x;
        __syncthreads();
    }
    hist_g[b * NBLK + t] = sd[t] - v;   // exclusive
    if (t == NBLK - 1) tot[b] = sd[t];
}

// exclusive scan of bucket totals -> bkt_ptr[0..NB]; ALSO converts W to f16.
__global__ __launch_bounds__(1024)
void bucket_scan2(const int* __restrict__ tot, int* __restrict__ bkt_ptr, int NB, int E,
                  const float* __restrict__ W, _Float16* __restrict__ W16)
{
    __shared__ int sd[1024];
    int t = threadIdx.x;
    // W fp32 -> f16 (16384 elements)
#pragma unroll
    for (int j = 0; j < 16; ++j) W16[t + j * 1024] = (_Float16)W[t + j * 1024];

    int v[4]; int s = 0;
#pragma unroll
    for (int j = 0; j < 4; ++j) {
        int idx = t * 4 + j;
        v[j] = (idx < NB) ? tot[idx] : 0;
        s += v[j];
    }
    sd[t] = s;
    __syncthreads();
    for (int off = 1; off < 1024; off <<= 1) {
        int x = (t >= off) ? sd[t - off] : 0;
        __syncthreads();
        sd[t] += x;
        __syncthreads();
    }
    int base = (t == 0) ? 0 : sd[t - 1];
#pragma unroll
    for (int j = 0; j < 4; ++j) {
        int idx = t * 4 + j;
        if (idx < NB) { bkt_ptr[idx] = base; base += v[j]; }
    }
    if (t == 0) bkt_ptr[NB] = E;
}

// scatter edges into bucket-contiguous storage; packed (col | rloc<<20, valbits)
__global__ __launch_bounds__(SCT)
void bucket_scatter(const int* __restrict__ rows, const int* __restrict__ cols,
                    const float* __restrict__ vals, const int* __restrict__ bkt_ptr,
                    const int* __restrict__ hist_g, uint2* __restrict__ edges,
                    int E, int chunk, int NB)
{
    __shared__ int cur[NBMAX];
    int tid = threadIdx.x, blk = blockIdx.x;
    for (int b = tid; b < NB; b += SCT)
        cur[b] = bkt_ptr[b] + hist_g[b * NBLK + blk];
    __syncthreads();
    int s = blk * chunk, e = min(E, s + chunk);
    for (int i = s + tid; i < e; i += SCT) {
        int r = rows[i];
        int b = r >> SHIFT;
        uint2 ed;
        ed.x = (unsigned)cols[i] | ((unsigned)(r & 31) << 20);
        ed.y = __float_as_uint(vals[i]);
        int p = atomicAdd(&cur[b], 1);
        edges[p] = ed;
    }
}

// ------- SpMM + GEMM2 fused: per-bucket sort, register accum, MFMA epilogue -
// block = 256 thr = 4 waves; bucket = 32 rows; wave w accumulates rows
// [w*8, w*8+8), lane l = true cols {2l, 2l+1}. Then temp tile -> LDS ->
// out[32x128] = prelu(T @ W16^T + bias) via 16 MFMAs/wave, fp32 store.
__global__ __launch_bounds__(256)
void spmm_fused(const int* __restrict__ bkt_ptr, const uint2* __restrict__ edges,
                const _Float16* __restrict__ h, const _Float16* __restrict__ W16,
                const float* __restrict__ bias, const float* __restrict__ alpha_p,
                float* __restrict__ out, int N)
{
    __shared__ uint2 eL[CAP];
    __shared__ uint2 eS[CAP];
    __shared__ _Float16 T[32 * LDK];
    __shared__ int bins[32], startS[33];

    const int tid  = threadIdx.x;
    const int wave = tid >> 6;
    const int lane = tid & 63;
    const int b    = blockIdx.x;
    const int s0   = bkt_ptr[b], e0 = bkt_ptr[b + 1];

    float acc[8][2] = {};

    for (int base = s0; base < e0; base += CAP) {
        const int n = min(CAP, e0 - base);
        if (tid < 32) bins[tid] = 0;
        __syncthreads();
        for (int i = tid; i < n; i += 256) {
            uint2 ed = edges[base + i];
            eL[i] = ed;
            atomicAdd(&bins[ed.x >> 20], 1);
        }
        __syncthreads();
        if (tid < 32) {                    // wave-parallel 32-bin inclusive scan
            int x = bins[tid];
#pragma unroll
            for (int off = 1; off < 32; off <<= 1) {
                int y = __shfl_up(x, off);
                if (tid >= off) x += y;
            }
            startS[tid + 1] = x;
            if (tid == 0) startS[0] = 0;
            bins[tid] = x - bins[tid];     // bins becomes running cursor (exclusive)
        }
        __syncthreads();
        for (int i = tid; i < n; i += 256) {
            uint2 ed = eL[i];
            int p = atomicAdd(&bins[ed.x >> 20], 1);
            eS[p] = ed;
        }
        __syncthreads();

#pragma unroll
        for (int j = 0; j < 8; ++j) {
            int r  = wave * 8 + j;
            int rs = startS[r], re = startS[r + 1];
            float a0r = acc[j][0], a1r = acc[j][1];
            int i = rs;
            for (; i + 7 < re; i += 8) {   // deep unroll: 8 gathers in flight
                uint2 q0 = eS[i],     q1 = eS[i + 1], q2 = eS[i + 2], q3 = eS[i + 3];
                uint2 q4 = eS[i + 4], q5 = eS[i + 5], q6 = eS[i + 6], q7 = eS[i + 7];
                half2v v0 = *(const half2v*)(h + (size_t)(q0.x & 0xFFFFF) * 128 + lane * 2);
                half2v v1 = *(const half2v*)(h + (size_t)(q1.x & 0xFFFFF) * 128 + lane * 2);
                half2v v2 = *(const half2v*)(h + (size_t)(q2.x & 0xFFFFF) * 128 + lane * 2);
                half2v v3 = *(const half2v*)(h + (size_t)(q3.x & 0xFFFFF) * 128 + lane * 2);
                half2v v4 = *(const half2v*)(h + (size_t)(q4.x & 0xFFFFF) * 128 + lane * 2);
                half2v v5 = *(const half2v*)(h + (size_t)(q5.x & 0xFFFFF) * 128 + lane * 2);
                half2v v6 = *(const half2v*)(h + (size_t)(q6.x & 0xFFFFF) * 128 + lane * 2);
                half2v v7 = *(const half2v*)(h + (size_t)(q7.x & 0xFFFFF) * 128 + lane * 2);
                float w0 = __uint_as_float(q0.y), w1 = __uint_as_float(q1.y);
                float w2 = __uint_as_float(q2.y), w3 = __uint_as_float(q3.y);
                float w4 = __uint_as_float(q4.y), w5 = __uint_as_float(q5.y);
                float w6 = __uint_as_float(q6.y), w7 = __uint_as_float(q7.y);
                a0r += w0 * (float)v0[0]; a1r += w0 * (float)v0[1];
                a0r += w1 * (float)v1[0]; a1r += w1 * (float)v1[1];
                a0r += w2 * (float)v2[0]; a1r += w2 * (float)v2[1];
                a0r += w3 * (float)v3[0]; a1r += w3 * (float)v3[1];
                a0r += w4 * (float)v4[0]; a1r += w4 * (float)v4[1];
                a0r += w5 * (float)v5[0]; a1r += w5 * (float)v5[1];
                a0r += w6 * (float)v6[0]; a1r += w6 * (float)v6[1];
                a0r += w7 * (float)v7[0]; a1r += w7 * (float)v7[1];
            }
            for (; i + 1 < re; i += 2) {
                uint2 q0 = eS[i], q1 = eS[i + 1];
                half2v v0 = *(const half2v*)(h + (size_t)(q0.x & 0xFFFFF) * 128 + lane * 2);
                half2v v1 = *(const half2v*)(h + (size_t)(q1.x & 0xFFFFF) * 128 + lane * 2);
                float w0 = __uint_as_float(q0.y), w1 = __uint_as_float(q1.y);
                a0r += w0 * (float)v0[0]; a1r += w0 * (float)v0[1];
                a0r += w1 * (float)v1[0]; a1r += w1 * (float)v1[1];
            }
            if (i < re) {
                uint2 q0 = eS[i];
                half2v v0 = *(const half2v*)(h + (size_t)(q0.x & 0xFFFFF) * 128 + lane * 2);
                float w0 = __uint_as_float(q0.y);
                a0r += w0 * (float)v0[0]; a1r += w0 * (float)v0[1];
            }
            acc[j][0] = a0r; acc[j][1] = a1r;
        }
        __syncthreads();   // protect eL/eS before next chunk
    }

    // temp tile -> LDS (f16), row stride LDK breaks MFMA-read conflicts
#pragma unroll
    for (int j = 0; j < 8; ++j) {
        half2v o = { (_Float16)acc[j][0], (_Float16)acc[j][1] };
        *(half2v*)(&T[(wave * 8 + j) * LDK + lane * 2]) = o;
    }
    __syncthreads();

    // GEMM2 epilogue: out[32x128] = prelu(T @ W16^T + bias)
    const float alpha = *alpha_p;
    const int l15  = lane & 15;
    const int quad = lane >> 4;
    floatx4 c[2][2] = {};   // m-tiles {0,16} x n-tiles {wave*2, wave*2+1}
#pragma unroll
    for (int k0 = 0; k0 < 128; k0 += 32) {
        half8 a0 = *(const half8*)(&T[(     l15) * LDK + k0 + quad * 8]);
        half8 a1 = *(const half8*)(&T[(16 + l15) * LDK + k0 + quad * 8]);
#pragma unroll
        for (int nt = 0; nt < 2; ++nt) {
            int nrow = (wave * 2 + nt) * 16 + l15;
            half8 bf = *(const half8*)(W16 + nrow * 128 + k0 + quad * 8);
            c[0][nt] = __builtin_amdgcn_mfma_f32_16x16x32_f16(a0, bf, c[0][nt], 0, 0, 0);
            c[1][nt] = __builtin_amdgcn_mfma_f32_16x16x32_f16(a1, bf, c[1][nt], 0, 0, 0);
        }
    }
    const int row0 = b << SHIFT;
#pragma unroll
    for (int mt = 0; mt < 2; ++mt) {
#pragma unroll
        for (int nt = 0; nt < 2; ++nt) {
            int col = (wave * 2 + nt) * 16 + l15;
            float bcol = bias[col];
#pragma unroll
            for (int r = 0; r < 4; ++r) {
                int row = row0 + mt * 16 + quad * 4 + r;
                if (row < N) {
                    float v = c[mt][nt][r] + bcol;
                    v = (v >= 0.f) ? v : alpha * v;
                    out[(size_t)row * 128 + col] = v;
                }
            }
        }
    }
}

// ---------------- launcher ----------------
static inline size_t align256(size_t x) { return (x + 255) & ~(size_t)255; }

extern "C" void kernel_launch(void* const* d_in, const int* in_sizes, int n_in,
                              void* d_out, int out_size, void* d_ws, size_t ws_size,
                              hipStream_t stream)
{
    const float* AX        = (const float*)d_in[0];
    const int*   A_row     = (const int*)  d_in[1];
    const int*   A_col     = (const int*)  d_in[2];
    const float* A_val     = (const float*)d_in[3];
    const float* Wr_w      = (const float*)d_in[4];
    const float* Wr_b      = (const float*)d_in[5];
    const float* W_w       = (const float*)d_in[6];
    const float* W_b       = (const float*)d_in[7];
    const float* g_alpha   = (const float*)d_in[8];
    const float* act_alpha = (const float*)d_in[9];

    const int N = in_sizes[0] / 128;
    const int E = in_sizes[1];
    const int NB = (N + 31) >> SHIFT;            // 3125
    const int chunk = (E + NBLK - 1) / NBLK;     // 12500

    char* ws = (char*)d_ws;
    size_t off = 0;
    _Float16* h      = (_Float16*)(ws + off); off += align256((size_t)N * 128 * 2);
    uint2*    edges  = (uint2*)   (ws + off); off += align256((size_t)E * 8);
    int*      hist_g = (int*)     (ws + off); off += align256((size_t)NB * NBLK * 4);
    int*      tot    = (int*)     (ws + off); off += align256((size_t)NB * 4);
    int*      bkt_ptr= (int*)     (ws + off); off += align256((size_t)(NB + 1) * 4);
    _Float16* W16    = (_Float16*)(ws + off); off += align256((size_t)128 * 128 * 2);
    (void)ws_size; (void)n_in; (void)out_size;

    const int gemm_grid = (N + 127) / 128;

    gemm128_prelu<<<gemm_grid, 256, 0, stream>>>(AX, Wr_w, Wr_b, g_alpha, h, N);

    bucket_hist<<<NBLK, SCT, 0, stream>>>(A_row, hist_g, E, chunk, NB);
    bucket_scan1<<<NB, NBLK, 0, stream>>>(hist_g, tot);
    bucket_scan2<<<1, 1024, 0, stream>>>(tot, bkt_ptr, NB, E, W_w, W16);
    bucket_scatter<<<NBLK, SCT, 0, stream>>>(A_row, A_col, A_val, bkt_ptr, hist_g, edges, E, chunk, NB);

    spmm_fused<<<NB, 256, 0, stream>>>(bkt_ptr, edges, h, W16, W_b, act_alpha,
                                       (float*)d_out, N);
}